// Round 8
// baseline (282.770 us; speedup 1.0000x reference)
//
#include <hip/hip_runtime.h>
#include <hip/hip_bf16.h>
#include <cstdint>
#include <cstddef>

using bf16 = __hip_bfloat16;
typedef __attribute__((ext_vector_type(4))) float f32x4;
typedef __attribute__((ext_vector_type(8))) short bf16x8;

#define D_MODEL 1024
#define SEQ     2048
#define NB      4
#define NHEAD   16
#define DHEAD   64
#define NROWS   (NB * SEQ)   // 8192

__device__ __forceinline__ void load_lds16(const void* g, void* l) {
  __builtin_amdgcn_global_load_lds(
      (const __attribute__((address_space(1))) unsigned int*)g,
      (__attribute__((address_space(3))) unsigned int*)l, 16, 0, 0);
}

__device__ __forceinline__ unsigned short f2bf(float f) {
  bf16 h = __float2bfloat16(f);
  return *(unsigned short*)&h;
}

// Truncating pack: two f32 -> packed bf16 pair (low = a, high = b). ~1 v_perm.
__device__ __forceinline__ unsigned pk_trunc(float a, float b) {
  union { float f; unsigned u; } ca, cb;
  ca.f = a; cb.f = b;
  return (ca.u >> 16) | (cb.u & 0xffff0000u);
}

// ---------------- LayerNorm: fp32 in, bf16 out; one wave per row ----------------
__global__ __launch_bounds__(256) void ln_kernel(
    const float* __restrict__ x, const float* __restrict__ g,
    const float* __restrict__ bb, bf16* __restrict__ xn) {
  int row  = blockIdx.x * 4 + (threadIdx.x >> 6);
  int lane = threadIdx.x & 63;
  const float4* xr = (const float4*)(x + (size_t)row * D_MODEL);
  float v[16], s = 0.f;
#pragma unroll
  for (int i = 0; i < 4; i++) {
    float4 t = xr[lane + 64 * i];
    v[4 * i] = t.x; v[4 * i + 1] = t.y; v[4 * i + 2] = t.z; v[4 * i + 3] = t.w;
    s += t.x + t.y + t.z + t.w;
  }
#pragma unroll
  for (int off = 32; off; off >>= 1) s += __shfl_xor(s, off, 64);
  float mean = s * (1.f / D_MODEL);
  float vs = 0.f;
#pragma unroll
  for (int i = 0; i < 16; i++) { float d = v[i] - mean; vs += d * d; }
#pragma unroll
  for (int off = 32; off; off >>= 1) vs += __shfl_xor(vs, off, 64);
  float rstd = rsqrtf(vs * (1.f / D_MODEL) + 1e-5f);
  ushort4* op = (ushort4*)(xn + (size_t)row * D_MODEL);
#pragma unroll
  for (int i = 0; i < 4; i++) {
    float4 gv = ((const float4*)g)[lane + 64 * i];
    float4 bv = ((const float4*)bb)[lane + 64 * i];
    ushort4 o;
    o.x = f2bf((v[4 * i]     - mean) * rstd * gv.x + bv.x);
    o.y = f2bf((v[4 * i + 1] - mean) * rstd * gv.y + bv.y);
    o.z = f2bf((v[4 * i + 2] - mean) * rstd * gv.z + bv.z);
    o.w = f2bf((v[4 * i + 3] - mean) * rstd * gv.w + bv.w);
    op[lane + 64 * i] = o;
  }
}

// ------- Fused transpose of both weights: fp32 in[1024][C] -> bf16 out[C][1024] -------
__global__ __launch_bounds__(256) void transpose_kernel(
    const float* __restrict__ w_qkv, bf16* __restrict__ wqkvT,
    const float* __restrict__ w_fc, bf16* __restrict__ wfcT) {
  __shared__ float tile[32][33];
  const float* in; bf16* out; int C, c0;
  if (blockIdx.x < 96) { in = w_qkv; out = wqkvT; C = 3072; c0 = blockIdx.x * 32; }
  else                 { in = w_fc;  out = wfcT;  C = 1024; c0 = (blockIdx.x - 96) * 32; }
  int r0 = blockIdx.y * 32;
  int tx = threadIdx.x & 31, ty = threadIdx.x >> 5;
  for (int i = ty; i < 32; i += 8)
    tile[i][tx] = in[(size_t)(r0 + i) * C + c0 + tx];
  __syncthreads();
  for (int i = ty; i < 32; i += 8)
    out[(size_t)(c0 + i) * 1024 + r0 + tx] = __float2bfloat16(tile[tx][i]);
}

__device__ __forceinline__ void store_ct(bf16* p, float v)  { *p = __float2bfloat16(v); }
__device__ __forceinline__ void store_ct(float* p, float v) { *p = v; }

// ======== Wave-autonomous GEMM (ZERO barriers in the K-loop) ========
// C[M,N] = A[M,K] @ Bt[N,K]^T + bias (+resid). 128x128 block tile, 4 waves 2x2.
// Each wave owns a PRIVATE 16 KB LDS region holding ITS 64-row A-half and
// 64-row B-half (sibling waves duplicate the fetch -- L2 absorbs it). All
// synchronization is per-wave hardware counters:
//   ds_read frags(t) -> lgkmcnt(0) -> issue 16 gload_lds(t+1) into same
//   region -> 32 MFMA -> vmcnt(0).
// No s_barrier anywhere in the loop: waves drift freely, so one wave's load
// wait is covered by other waves' MFMA (m114 co-scheduling), instead of all
// waves draining together at a barrier (the measured failure of the lockstep
// structure: gemm2 at ~220 TF, r6's 8-phase at 22% MfmaUtil / 13% VALUBusy).
// Swizzle math identical to the verified scheme (row&7 XOR, 64-elem rows).
template <int K, int SPLIT, int RESID, typename CT>
__global__ __launch_bounds__(256) void gemm_wa(
    const bf16* __restrict__ A, const bf16* __restrict__ Bt,
    const float* __restrict__ bias, const float* __restrict__ resid,
    CT* __restrict__ C, bf16* __restrict__ vt, int M, int N) {
  __shared__ __attribute__((aligned(16))) bf16 lds[4 * 8192];  // 64 KB: 16 KB/wave
  int tid = threadIdx.x, wave = tid >> 6, lane = tid & 63;
  int ntiles = N >> 7;
  int bm = blockIdx.x / ntiles, bn = blockIdx.x % ntiles;
  int m0 = bm << 7, n0 = bn << 7;
  int wm = (wave >> 1) << 6, wn = (wave & 1) << 6;
  int row8 = lane >> 3, ch8 = lane & 7;
  int sw8 = ((ch8 ^ row8) << 3);          // swizzled source chunk (elements)
  int frow = lane & 15, quad = lane >> 4;
  bf16* Aw = lds + wave * 8192;           // wave-private: [A-half 4096][B-half 4096]
  bf16* Bw = Aw + 4096;

  const bf16* Asrc = A  + (size_t)(m0 + wm + row8) * K + sw8;
  const bf16* Bsrc = Bt + (size_t)(n0 + wn + row8) * K + sw8;

  // Stage this wave's 64x64 A-half + 64x64 B-half (16 x gload_lds, 16 KB).
  // Call c covers rows 8c..8c+7: LDS[row][ch] = global[row][ch ^ (row&7)].
  auto stage = [&](const bf16* As, const bf16* Bs) {
#pragma unroll
    for (int c = 0; c < 8; c++)
      load_lds16(As + (size_t)(8 * c) * K, (char*)Aw + c * 1024 + lane * 16);
#pragma unroll
    for (int c = 0; c < 8; c++)
      load_lds16(Bs + (size_t)(8 * c) * K, (char*)Bw + c * 1024 + lane * 16);
  };

  // Prologue: stage K-tile 0, wait own loads only (per-wave vmcnt).
  stage(Asrc, Bsrc);
  Asrc += 64; Bsrc += 64;
  asm volatile("s_waitcnt vmcnt(0)" ::: "memory");
  __builtin_amdgcn_sched_barrier(0);

  f32x4 acc[4][4] = {};
#pragma unroll 1
  for (int t = 0; t < K / 64 - 1; t++) {
    // frags of tile t (register)
    bf16x8 af[4][2], bv[4][2];
#pragma unroll
    for (int i = 0; i < 4; i++)
#pragma unroll
      for (int kk = 0; kk < 2; kk++) {
        int e = (((kk * 4 + quad) ^ (frow & 7)) << 3);
        af[i][kk] = *(const bf16x8*)&Aw[(i * 16 + frow) * 64 + e];
        bv[i][kk] = *(const bf16x8*)&Bw[(i * 16 + frow) * 64 + e];
      }
    asm volatile("s_waitcnt lgkmcnt(0)" ::: "memory");   // frags in regs; region dead
    __builtin_amdgcn_sched_barrier(0);
    stage(Asrc, Bsrc);                                   // tile t+1 -> same region
    Asrc += 64; Bsrc += 64;
    __builtin_amdgcn_sched_barrier(0);
    __builtin_amdgcn_s_setprio(1);
#pragma unroll
    for (int i = 0; i < 4; i++)
#pragma unroll
      for (int j = 0; j < 4; j++) {
        acc[i][j] = __builtin_amdgcn_mfma_f32_16x16x32_bf16(af[i][0], bv[j][0], acc[i][j], 0, 0, 0);
        acc[i][j] = __builtin_amdgcn_mfma_f32_16x16x32_bf16(af[i][1], bv[j][1], acc[i][j], 0, 0, 0);
      }
    __builtin_amdgcn_s_setprio(0);
    asm volatile("s_waitcnt vmcnt(0)" ::: "memory");     // tile t+1 resident
    __builtin_amdgcn_sched_barrier(0);
  }
  // Last K-tile: no staging.
  {
    bf16x8 af[4][2], bv[4][2];
#pragma unroll
    for (int i = 0; i < 4; i++)
#pragma unroll
      for (int kk = 0; kk < 2; kk++) {
        int e = (((kk * 4 + quad) ^ (frow & 7)) << 3);
        af[i][kk] = *(const bf16x8*)&Aw[(i * 16 + frow) * 64 + e];
        bv[i][kk] = *(const bf16x8*)&Bw[(i * 16 + frow) * 64 + e];
      }
    asm volatile("s_waitcnt lgkmcnt(0)" ::: "memory");
    __builtin_amdgcn_sched_barrier(0);
#pragma unroll
    for (int i = 0; i < 4; i++)
#pragma unroll
      for (int j = 0; j < 4; j++) {
        acc[i][j] = __builtin_amdgcn_mfma_f32_16x16x32_bf16(af[i][0], bv[j][0], acc[i][j], 0, 0, 0);
        acc[i][j] = __builtin_amdgcn_mfma_f32_16x16x32_bf16(af[i][1], bv[j][1], acc[i][j], 0, 0, 0);
      }
  }

  // Epilogue (identical math/order to the verified gemm_bt).
#pragma unroll
  for (int i = 0; i < 4; i++) {
    int row0 = m0 + wm + i * 16 + (quad << 2);
#pragma unroll
    for (int j = 0; j < 4; j++) {
      int col = n0 + wn + j * 16 + frow;
      float bvs = bias[col];
      if (SPLIT && col >= 2048) {           // V third -> permuted transposed vt
        int hd = col - 2048;
        int b = row0 >> 11, seq0 = row0 & 2047;
        int within = seq0 & 63, mt = within >> 4, q4 = (within >> 2) & 3;
        int pos = (seq0 & ~63) + ((mt >> 1) << 5) + (q4 << 3) + ((mt & 1) << 2);
        ushort4 pk;
        pk.x = f2bf(acc[i][j][0] + bvs);
        pk.y = f2bf(acc[i][j][1] + bvs);
        pk.z = f2bf(acc[i][j][2] + bvs);
        pk.w = f2bf(acc[i][j][3] + bvs);
        *(ushort4*)&vt[((size_t)(b * 1024 + hd)) * SEQ + pos] = pk;
      } else {
        int stride = SPLIT ? 2048 : N;
        // Q pre-scale: 1/sqrt(64) * log2(e) -> scores come out in exp2 domain
        float scale = (SPLIT && col < 1024) ? 0.18033688f : 1.0f;
#pragma unroll
        for (int r = 0; r < 4; r++) {
          size_t idx = (size_t)(row0 + r) * stride + col;
          float val = (acc[i][j][r] + bvs) * scale;
          if (RESID) val += resid[idx];
          store_ct(&C[idx], val);
        }
      }
    }
  }
}

// ---- Flash attention helpers (round-3 best: simple dbuf, one barrier/tile) ----

__device__ __forceinline__ void stage_kv(
    const bf16* Kp0, const bf16* Kp1, const bf16* Vp0, const bf16* Vp1,
    bf16* KB, bf16* VB, int tid) {
  load_lds16(Kp0, (char*)KB + tid * 16);
  load_lds16(Kp1, (char*)KB + 4096 + tid * 16);
  load_lds16(Vp0, (char*)VB + tid * 16);
  load_lds16(Vp1, (char*)VB + 4096 + tid * 16);
}

// One KV tile: S^T = K @ Q^T; p = 2^s packed to bf16 in-register; O^T += V^T @ P^T.
__device__ __forceinline__ void kv_tile(
    const bf16* KL, const bf16* VL, int frow, int e0,
    const bf16x8 (&qf)[2][2], f32x4 (&l4)[2], f32x4 (&o)[4][2]) {
  f32x4 s[4][2] = {};
#pragma unroll
  for (int mt = 0; mt < 4; mt++) {
    bf16x8 af0 = *(const bf16x8*)&KL[(mt * 16 + frow) * 64 + e0];
    bf16x8 af1 = *(const bf16x8*)&KL[(mt * 16 + frow) * 64 + (e0 ^ 32)];
#pragma unroll
    for (int qt2 = 0; qt2 < 2; qt2++) {
      s[mt][qt2] = __builtin_amdgcn_mfma_f32_16x16x32_bf16(af0, qf[qt2][0], s[mt][qt2], 0, 0, 0);
      s[mt][qt2] = __builtin_amdgcn_mfma_f32_16x16x32_bf16(af1, qf[qt2][1], s[mt][qt2], 0, 0, 0);
    }
  }
  uint2 pk[2][4];
#pragma unroll
  for (int qt2 = 0; qt2 < 2; qt2++)
#pragma unroll
    for (int mt = 0; mt < 4; mt++) {
      f32x4 pv;
      pv[0] = __builtin_amdgcn_exp2f(s[mt][qt2][0]);
      pv[1] = __builtin_amdgcn_exp2f(s[mt][qt2][1]);
      pv[2] = __builtin_amdgcn_exp2f(s[mt][qt2][2]);
      pv[3] = __builtin_amdgcn_exp2f(s[mt][qt2][3]);
      l4[qt2] += pv;
      pk[qt2][mt].x = pk_trunc(pv[0], pv[1]);
      pk[qt2][mt].y = pk_trunc(pv[2], pv[3]);
    }
#pragma unroll
  for (int dt = 0; dt < 4; dt++) {
    bf16x8 vf0 = *(const bf16x8*)&VL[(dt * 16 + frow) * 64 + e0];
    bf16x8 vf1 = *(const bf16x8*)&VL[(dt * 16 + frow) * 64 + (e0 ^ 32)];
#pragma unroll
    for (int qt2 = 0; qt2 < 2; qt2++) {
      union { unsigned u[4]; bf16x8 v; } pf0, pf1;
      pf0.u[0] = pk[qt2][0].x; pf0.u[1] = pk[qt2][0].y;
      pf0.u[2] = pk[qt2][1].x; pf0.u[3] = pk[qt2][1].y;
      pf1.u[0] = pk[qt2][2].x; pf1.u[1] = pk[qt2][2].y;
      pf1.u[2] = pk[qt2][3].x; pf1.u[3] = pk[qt2][3].y;
      o[dt][qt2] = __builtin_amdgcn_mfma_f32_16x16x32_bf16(vf0, pf0.v, o[dt][qt2], 0, 0, 0);
      o[dt][qt2] = __builtin_amdgcn_mfma_f32_16x16x32_bf16(vf1, pf1.v, o[dt][qt2], 0, 0, 0);
    }
  }
}

// ---- Flash attention (S^T form, exp2-domain, no-max softmax, register-P) ----
// Round-3 best config: 2D grid (bh, qt), dbuf KV via dead Qlds, 1 barrier/tile.
__global__ __launch_bounds__(256, 4) void attn_kernel(
    const bf16* __restrict__ qk, const bf16* __restrict__ vt,
    bf16* __restrict__ aout) {
  int bh = blockIdx.x;   // 0..63 == b*16+h
  int qt = blockIdx.y;   // 0..15
  int bb = bh >> 4, h = bh & 15;
  const bf16* Qg = qk + (size_t)bb * SEQ * 2048 + h * DHEAD;
  const bf16* Kg = Qg + D_MODEL;
  const bf16* Vg = vt + (size_t)bh * DHEAD * SEQ;

  __shared__ __attribute__((aligned(16))) bf16 Qlds[128 * 64];   // 16 KB; KV buf1 after prologue
  __shared__ __attribute__((aligned(16))) bf16 Klds[64 * 64];    //  8 KB; KV buf0 K
  __shared__ __attribute__((aligned(16))) bf16 Vlds[64 * 64];    //  8 KB; KV buf0 V

  int tid = threadIdx.x, wave = tid >> 6, lane = tid & 63;
  int prow = tid >> 3, pch = tid & 7;
  int lch8 = ((pch ^ (prow & 7)) << 3);
  int frow = lane & 15, quad = lane >> 4;
  int e0 = ((quad ^ (frow & 7)) << 3);
  int q0 = qt * 128;

  bf16* K0 = Klds;  bf16* V0 = Vlds;
  bf16* K1 = Qlds;  bf16* V1 = Qlds + 64 * 64;

  const bf16* Kp0 = Kg + (size_t)prow * 2048 + lch8;
  const bf16* Kp1 = Kg + (size_t)(32 + prow) * 2048 + lch8;
  const bf16* Vp0 = Vg + (size_t)prow * SEQ + lch8;
  const bf16* Vp1 = Vg + (size_t)(32 + prow) * SEQ + lch8;
  const size_t KT = (size_t)1 << 17;

#pragma unroll
  for (int s2 = 0; s2 < 4; s2++)
    load_lds16(Qg + (size_t)(q0 + s2 * 32 + prow) * 2048 + lch8,
               (char*)Qlds + s2 * 4096 + tid * 16);
  __syncthreads();
  bf16x8 qf[2][2];
#pragma unroll
  for (int qt2 = 0; qt2 < 2; qt2++)
#pragma unroll
    for (int kk = 0; kk < 2; kk++)
      qf[qt2][kk] =
          *(const bf16x8*)&Qlds[(wave * 32 + qt2 * 16 + frow) * 64 + (e0 ^ (kk * 32))];
  stage_kv(Kp0, Kp1, Vp0, Vp1, K0, V0, tid);
  __syncthreads();

  f32x4 l4[2] = {};
  f32x4 o[4][2] = {};

#pragma unroll 1
  for (int kt = 0; kt < 30; kt += 2) {
    stage_kv(Kp0 + KT, Kp1 + KT, Vp0 + 64, Vp1 + 64, K1, V1, tid);
    kv_tile(K0, V0, frow, e0, qf, l4, o);
    __syncthreads();
    stage_kv(Kp0 + 2 * KT, Kp1 + 2 * KT, Vp0 + 128, Vp1 + 128, K0, V0, tid);
    kv_tile(K1, V1, frow, e0, qf, l4, o);
    __syncthreads();
    Kp0 += 2 * KT; Kp1 += 2 * KT; Vp0 += 128; Vp1 += 128;
  }
  stage_kv(Kp0 + KT, Kp1 + KT, Vp0 + 64, Vp1 + 64, K1, V1, tid);
  kv_tile(K0, V0, frow, e0, qf, l4, o);
  __syncthreads();
  kv_tile(K1, V1, frow, e0, qf, l4, o);

  float linv[2];
#pragma unroll
  for (int qt2 = 0; qt2 < 2; qt2++) {
    float v = (l4[qt2][0] + l4[qt2][1]) + (l4[qt2][2] + l4[qt2][3]);
    v += __shfl_xor(v, 16, 64);
    v += __shfl_xor(v, 32, 64);
    linv[qt2] = 1.f / v;
  }

  __syncthreads();
  bf16* Tw = (wave == 0) ? Qlds
           : (wave == 1) ? Qlds + 32 * 80
           : (wave == 2) ? Klds : Vlds;
#pragma unroll
  for (int qt2 = 0; qt2 < 2; qt2++)
#pragma unroll
    for (int dt = 0; dt < 4; dt++) {
      ushort4 pk;
      pk.x = f2bf(o[dt][qt2][0] * linv[qt2]);
      pk.y = f2bf(o[dt][qt2][1] * linv[qt2]);
      pk.z = f2bf(o[dt][qt2][2] * linv[qt2]);
      pk.w = f2bf(o[dt][qt2][3] * linv[qt2]);
      *(ushort4*)&Tw[(qt2 * 16 + frow) * 80 + dt * 16 + quad * 4] = pk;
    }
  int rq = lane >> 1, d0 = (lane & 1) * 32;
  size_t grow = (size_t)(bb * SEQ + q0 + wave * 32 + rq);
#pragma unroll
  for (int i = 0; i < 4; i++) {
    bf16x8 v8 = *(const bf16x8*)&Tw[rq * 80 + d0 + i * 8];
    *(bf16x8*)&aout[grow * D_MODEL + h * DHEAD + d0 + i * 8] = v8;
  }
}

extern "C" void kernel_launch(void* const* d_in, const int* in_sizes, int n_in,
                              void* d_out, int out_size, void* d_ws, size_t ws_size,
                              hipStream_t stream) {
  const float* x     = (const float*)d_in[0];
  const float* w_qkv = (const float*)d_in[1];
  const float* b_qkv = (const float*)d_in[2];
  const float* w_fc  = (const float*)d_in[3];
  const float* b_fc  = (const float*)d_in[4];
  const float* ln_g  = (const float*)d_in[5];
  const float* ln_b  = (const float*)d_in[6];
  float* out = (float*)d_out;

  char* ws = (char*)d_ws;
  bf16* xn    = (bf16*)(ws);                 // 16 MB (aliased by aout after gemm1)
  bf16* wqkvT = (bf16*)(ws + (16u << 20));   //  6 MB
  bf16* wfcT  = (bf16*)(ws + (22u << 20));   //  2 MB
  bf16* qk    = (bf16*)(ws + (24u << 20));   // 32 MB
  bf16* vt    = (bf16*)(ws + (56u << 20));   // 16 MB -> 72 MB total
  bf16* aout  = (bf16*)(ws);                 // reuses xn region

  ln_kernel<<<NROWS / 4, 256, 0, stream>>>(x, ln_g, ln_b, xn);
  transpose_kernel<<<dim3(128, 32), 256, 0, stream>>>(w_qkv, wqkvT, w_fc, wfcT);
  gemm_wa<1024, 1, 0, bf16><<<(NROWS / 128) * (3 * D_MODEL / 128), 256, 0, stream>>>(
      xn, wqkvT, b_qkv, nullptr, qk, vt, NROWS, 3 * D_MODEL);
  attn_kernel<<<dim3(NB * NHEAD, SEQ / 128), 256, 0, stream>>>(qk, vt, aout);
  gemm_wa<1024, 0, 1, float><<<(NROWS / 128) * (D_MODEL / 128), 256, 0, stream>>>(
      aout, wfcT, b_fc, x, out, nullptr, NROWS, D_MODEL);
}

// Round 9
// 265.079 us; speedup vs baseline: 1.0667x; 1.0667x over previous
//
#include <hip/hip_runtime.h>
#include <hip/hip_bf16.h>
#include <cstdint>
#include <cstddef>

using bf16 = __hip_bfloat16;
typedef __attribute__((ext_vector_type(4))) float f32x4;
typedef __attribute__((ext_vector_type(8))) short bf16x8;

#define D_MODEL 1024
#define SEQ     2048
#define NB      4
#define NHEAD   16
#define DHEAD   64
#define NROWS   (NB * SEQ)   // 8192

__device__ __forceinline__ void load_lds16(const void* g, void* l) {
  __builtin_amdgcn_global_load_lds(
      (const __attribute__((address_space(1))) unsigned int*)g,
      (__attribute__((address_space(3))) unsigned int*)l, 16, 0, 0);
}

__device__ __forceinline__ unsigned short f2bf(float f) {
  bf16 h = __float2bfloat16(f);
  return *(unsigned short*)&h;
}

// Truncating pack: two f32 -> packed bf16 pair (low = a, high = b). ~1 v_perm.
__device__ __forceinline__ unsigned pk_trunc(float a, float b) {
  union { float f; unsigned u; } ca, cb;
  ca.f = a; cb.f = b;
  return (ca.u >> 16) | (cb.u & 0xffff0000u);
}

// ---- Fused prep: LN (blocks 0..2047) + weight transpose (blocks 2048..6143) ----
// One launch instead of two (saves a serialized inter-kernel gap; both parts
// are memory-bound on disjoint data; branch is uniform per block).
__global__ __launch_bounds__(256) void prep_kernel(
    const float* __restrict__ x, const float* __restrict__ g,
    const float* __restrict__ bb, bf16* __restrict__ xn,
    const float* __restrict__ w_qkv, bf16* __restrict__ wqkvT,
    const float* __restrict__ w_fc, bf16* __restrict__ wfcT) {
  __shared__ float tile[32][33];
  if (blockIdx.x < 2048) {
    // ---------- LayerNorm: fp32 in, bf16 out; one wave per row ----------
    int row  = blockIdx.x * 4 + (threadIdx.x >> 6);
    int lane = threadIdx.x & 63;
    const float4* xr = (const float4*)(x + (size_t)row * D_MODEL);
    float v[16], s = 0.f;
#pragma unroll
    for (int i = 0; i < 4; i++) {
      float4 t = xr[lane + 64 * i];
      v[4 * i] = t.x; v[4 * i + 1] = t.y; v[4 * i + 2] = t.z; v[4 * i + 3] = t.w;
      s += t.x + t.y + t.z + t.w;
    }
#pragma unroll
    for (int off = 32; off; off >>= 1) s += __shfl_xor(s, off, 64);
    float mean = s * (1.f / D_MODEL);
    float vs = 0.f;
#pragma unroll
    for (int i = 0; i < 16; i++) { float d = v[i] - mean; vs += d * d; }
#pragma unroll
    for (int off = 32; off; off >>= 1) vs += __shfl_xor(vs, off, 64);
    float rstd = rsqrtf(vs * (1.f / D_MODEL) + 1e-5f);
    ushort4* op = (ushort4*)(xn + (size_t)row * D_MODEL);
#pragma unroll
    for (int i = 0; i < 4; i++) {
      float4 gv = ((const float4*)g)[lane + 64 * i];
      float4 bv = ((const float4*)bb)[lane + 64 * i];
      ushort4 o;
      o.x = f2bf((v[4 * i]     - mean) * rstd * gv.x + bv.x);
      o.y = f2bf((v[4 * i + 1] - mean) * rstd * gv.y + bv.y);
      o.z = f2bf((v[4 * i + 2] - mean) * rstd * gv.z + bv.z);
      o.w = f2bf((v[4 * i + 3] - mean) * rstd * gv.w + bv.w);
      op[lane + 64 * i] = o;
    }
  } else {
    // ------ Transpose fp32 in[1024][C] -> bf16 out[C][1024] (32x32 tiles) ------
    int b2 = blockIdx.x - 2048;       // 0..4095
    int bx = b2 & 127, by = b2 >> 7;  // bx: col-block, by: row-block (32 rows)
    const float* in; bf16* out; int C, c0;
    if (bx < 96) { in = w_qkv; out = wqkvT; C = 3072; c0 = bx * 32; }
    else         { in = w_fc;  out = wfcT;  C = 1024; c0 = (bx - 96) * 32; }
    int r0 = by * 32;
    int tx = threadIdx.x & 31, ty = threadIdx.x >> 5;
    for (int i = ty; i < 32; i += 8)
      tile[i][tx] = in[(size_t)(r0 + i) * C + c0 + tx];
    __syncthreads();
    for (int i = ty; i < 32; i += 8)
      out[(size_t)(c0 + i) * 1024 + r0 + tx] = __float2bfloat16(tile[tx][i]);
  }
}

__device__ __forceinline__ void store_ct(bf16* p, float v)  { *p = __float2bfloat16(v); }
__device__ __forceinline__ void store_ct(float* p, float v) { *p = v; }

// ------- GEMM: C[M,N] = A[M,K](bf16) @ Bt[N,K](bf16)^T + bias (r3-exact) -------
// BK=64, XOR-swizzled LDS, 2-barrier loop, 128x128 tile. Used for the QKV gemm.
template <int SPLIT, int RESID, typename CT>
__global__ __launch_bounds__(256) void gemm_bt(
    const bf16* __restrict__ A, const bf16* __restrict__ Bt,
    const float* __restrict__ bias, const float* __restrict__ resid,
    CT* __restrict__ C, bf16* __restrict__ vt, int M, int N, int K) {
  __shared__ __attribute__((aligned(16))) bf16 Alds[128 * 64];  // 16 KB
  __shared__ __attribute__((aligned(16))) bf16 Blds[128 * 64];  // 16 KB
  int tid = threadIdx.x, wave = tid >> 6, lane = tid & 63;
  int ntiles = N >> 7;
  int bm = blockIdx.x / ntiles, bn = blockIdx.x % ntiles;
  int m0 = bm << 7, n0 = bn << 7;
  int wm = (wave >> 1) << 6, wn = (wave & 1) << 6;
  int srow = tid >> 3;                        // 0..31 (row within 32-row stage block)
  int sw8  = (((tid & 7) ^ (srow & 7)) << 3); // swizzled source chunk (elements)
  int frow = lane & 15, quad = lane >> 4;
  const bf16* Ap[4];
  const bf16* Bp[4];
#pragma unroll
  for (int s = 0; s < 4; s++) {
    Ap[s] = A  + (size_t)(m0 + s * 32 + srow) * K + sw8;
    Bp[s] = Bt + (size_t)(n0 + s * 32 + srow) * K + sw8;
  }
  f32x4 acc[4][4] = {};
  for (int k0 = 0; k0 < K; k0 += 64) {
    __syncthreads();
#pragma unroll
    for (int s = 0; s < 4; s++) {
      load_lds16(Ap[s], (char*)Alds + s * 4096 + tid * 16);
      load_lds16(Bp[s], (char*)Blds + s * 4096 + tid * 16);
      Ap[s] += 64; Bp[s] += 64;
    }
    __syncthreads();
    bf16x8 af[4][2], bv[4][2];
#pragma unroll
    for (int i = 0; i < 4; i++)
#pragma unroll
      for (int kk = 0; kk < 2; kk++) {
        int e = (((kk * 4 + quad) ^ (frow & 7)) << 3);
        af[i][kk] = *(const bf16x8*)&Alds[(wm + i * 16 + frow) * 64 + e];
        bv[i][kk] = *(const bf16x8*)&Blds[(wn + i * 16 + frow) * 64 + e];
      }
#pragma unroll
    for (int i = 0; i < 4; i++)
#pragma unroll
      for (int j = 0; j < 4; j++) {
        acc[i][j] = __builtin_amdgcn_mfma_f32_16x16x32_bf16(af[i][0], bv[j][0], acc[i][j], 0, 0, 0);
        acc[i][j] = __builtin_amdgcn_mfma_f32_16x16x32_bf16(af[i][1], bv[j][1], acc[i][j], 0, 0, 0);
      }
  }
#pragma unroll
  for (int i = 0; i < 4; i++) {
    int row0 = m0 + wm + i * 16 + (quad << 2);
#pragma unroll
    for (int j = 0; j < 4; j++) {
      int col = n0 + wn + j * 16 + frow;
      float bvs = bias[col];
      if (SPLIT && col >= 2048) {           // V third -> permuted transposed vt
        int hd = col - 2048;
        int b = row0 >> 11, seq0 = row0 & 2047;
        int within = seq0 & 63, mt = within >> 4, q4 = (within >> 2) & 3;
        int pos = (seq0 & ~63) + ((mt >> 1) << 5) + (q4 << 3) + ((mt & 1) << 2);
        ushort4 pk;
        pk.x = f2bf(acc[i][j][0] + bvs);
        pk.y = f2bf(acc[i][j][1] + bvs);
        pk.z = f2bf(acc[i][j][2] + bvs);
        pk.w = f2bf(acc[i][j][3] + bvs);
        *(ushort4*)&vt[((size_t)(b * 1024 + hd)) * SEQ + pos] = pk;
      } else {
        int stride = SPLIT ? 2048 : N;
        // Q pre-scale: 1/sqrt(64) * log2(e) -> scores come out in exp2 domain
        float scale = (SPLIT && col < 1024) ? 0.18033688f : 1.0f;
#pragma unroll
        for (int r = 0; r < 4; r++) {
          size_t idx = (size_t)(row0 + r) * stride + col;
          float val = (acc[i][j][r] + bvs) * scale;
          if (RESID) val += resid[idx];
          store_ct(&C[idx], val);
        }
      }
    }
  }
}

// ------- FC GEMM, 128x64 tile: out[8192,1024] = aout @ wfcT^T + b_fc + x -------
// The 128x128 version yields only 512 blocks = 2 blocks/CU -- half the CU
// slots empty and almost no cross-wave latency cover (latency-bound regime).
// 128x64 doubles the grid to 1024 = 4 blocks/CU fully resident, halves the
// per-block critical path. Same verified swizzle/staging math; RESID epilogue
// bit-identical to gemm_bt<0,1,float>.
__global__ __launch_bounds__(256) void gemm_fc64(
    const bf16* __restrict__ A, const bf16* __restrict__ Bt,
    const float* __restrict__ bias, const float* __restrict__ resid,
    float* __restrict__ out) {
  __shared__ __attribute__((aligned(16))) bf16 Alds[128 * 64];  // 16 KB
  __shared__ __attribute__((aligned(16))) bf16 Blds[64 * 64];   //  8 KB
  int tid = threadIdx.x, wave = tid >> 6, lane = tid & 63;
  int bm = blockIdx.x >> 4, bn = blockIdx.x & 15;   // 64 x 16 = 1024 blocks
  int m0 = bm << 7, n0 = bn << 6;
  int wm = (wave >> 1) << 6, wn = (wave & 1) << 5;  // wave tile 64x32
  int srow = tid >> 3;
  int sw8  = (((tid & 7) ^ (srow & 7)) << 3);
  int frow = lane & 15, quad = lane >> 4;
  const bf16* Ap[4];
  const bf16* Bp[2];
#pragma unroll
  for (int s = 0; s < 4; s++)
    Ap[s] = A + (size_t)(m0 + s * 32 + srow) * 1024 + sw8;
#pragma unroll
  for (int s = 0; s < 2; s++)
    Bp[s] = Bt + (size_t)(n0 + s * 32 + srow) * 1024 + sw8;
  f32x4 acc[4][2] = {};
  for (int k0 = 0; k0 < 1024; k0 += 64) {
    __syncthreads();
#pragma unroll
    for (int s = 0; s < 4; s++) {
      load_lds16(Ap[s], (char*)Alds + s * 4096 + tid * 16);
      Ap[s] += 64;
    }
#pragma unroll
    for (int s = 0; s < 2; s++) {
      load_lds16(Bp[s], (char*)Blds + s * 4096 + tid * 16);
      Bp[s] += 64;
    }
    __syncthreads();
    bf16x8 af[4][2], bv[2][2];
#pragma unroll
    for (int kk = 0; kk < 2; kk++) {
      int e = (((kk * 4 + quad) ^ (frow & 7)) << 3);
#pragma unroll
      for (int i = 0; i < 4; i++)
        af[i][kk] = *(const bf16x8*)&Alds[(wm + i * 16 + frow) * 64 + e];
#pragma unroll
      for (int j = 0; j < 2; j++)
        bv[j][kk] = *(const bf16x8*)&Blds[(wn + j * 16 + frow) * 64 + e];
    }
#pragma unroll
    for (int i = 0; i < 4; i++)
#pragma unroll
      for (int j = 0; j < 2; j++) {
        acc[i][j] = __builtin_amdgcn_mfma_f32_16x16x32_bf16(af[i][0], bv[j][0], acc[i][j], 0, 0, 0);
        acc[i][j] = __builtin_amdgcn_mfma_f32_16x16x32_bf16(af[i][1], bv[j][1], acc[i][j], 0, 0, 0);
      }
  }
#pragma unroll
  for (int i = 0; i < 4; i++) {
    int row0 = m0 + wm + i * 16 + (quad << 2);
#pragma unroll
    for (int j = 0; j < 2; j++) {
      int col = n0 + wn + j * 16 + frow;
      float bvs = bias[col];
#pragma unroll
      for (int r = 0; r < 4; r++) {
        size_t idx = (size_t)(row0 + r) * 1024 + col;
        out[idx] = (acc[i][j][r] + bvs) + resid[idx];
      }
    }
  }
}

// ---- Flash attention helpers (round-3 best: simple dbuf, one barrier/tile) ----

__device__ __forceinline__ void stage_kv(
    const bf16* Kp0, const bf16* Kp1, const bf16* Vp0, const bf16* Vp1,
    bf16* KB, bf16* VB, int tid) {
  load_lds16(Kp0, (char*)KB + tid * 16);
  load_lds16(Kp1, (char*)KB + 4096 + tid * 16);
  load_lds16(Vp0, (char*)VB + tid * 16);
  load_lds16(Vp1, (char*)VB + 4096 + tid * 16);
}

// One KV tile: S^T = K @ Q^T; p = 2^s packed to bf16 in-register; O^T += V^T @ P^T.
__device__ __forceinline__ void kv_tile(
    const bf16* KL, const bf16* VL, int frow, int e0,
    const bf16x8 (&qf)[2][2], f32x4 (&l4)[2], f32x4 (&o)[4][2]) {
  f32x4 s[4][2] = {};
#pragma unroll
  for (int mt = 0; mt < 4; mt++) {
    bf16x8 af0 = *(const bf16x8*)&KL[(mt * 16 + frow) * 64 + e0];
    bf16x8 af1 = *(const bf16x8*)&KL[(mt * 16 + frow) * 64 + (e0 ^ 32)];
#pragma unroll
    for (int qt2 = 0; qt2 < 2; qt2++) {
      s[mt][qt2] = __builtin_amdgcn_mfma_f32_16x16x32_bf16(af0, qf[qt2][0], s[mt][qt2], 0, 0, 0);
      s[mt][qt2] = __builtin_amdgcn_mfma_f32_16x16x32_bf16(af1, qf[qt2][1], s[mt][qt2], 0, 0, 0);
    }
  }
  uint2 pk[2][4];
#pragma unroll
  for (int qt2 = 0; qt2 < 2; qt2++)
#pragma unroll
    for (int mt = 0; mt < 4; mt++) {
      f32x4 pv;
      pv[0] = __builtin_amdgcn_exp2f(s[mt][qt2][0]);
      pv[1] = __builtin_amdgcn_exp2f(s[mt][qt2][1]);
      pv[2] = __builtin_amdgcn_exp2f(s[mt][qt2][2]);
      pv[3] = __builtin_amdgcn_exp2f(s[mt][qt2][3]);
      l4[qt2] += pv;
      pk[qt2][mt].x = pk_trunc(pv[0], pv[1]);
      pk[qt2][mt].y = pk_trunc(pv[2], pv[3]);
    }
#pragma unroll
  for (int dt = 0; dt < 4; dt++) {
    bf16x8 vf0 = *(const bf16x8*)&VL[(dt * 16 + frow) * 64 + e0];
    bf16x8 vf1 = *(const bf16x8*)&VL[(dt * 16 + frow) * 64 + (e0 ^ 32)];
#pragma unroll
    for (int qt2 = 0; qt2 < 2; qt2++) {
      union { unsigned u[4]; bf16x8 v; } pf0, pf1;
      pf0.u[0] = pk[qt2][0].x; pf0.u[1] = pk[qt2][0].y;
      pf0.u[2] = pk[qt2][1].x; pf0.u[3] = pk[qt2][1].y;
      pf1.u[0] = pk[qt2][2].x; pf1.u[1] = pk[qt2][2].y;
      pf1.u[2] = pk[qt2][3].x; pf1.u[3] = pk[qt2][3].y;
      o[dt][qt2] = __builtin_amdgcn_mfma_f32_16x16x32_bf16(vf0, pf0.v, o[dt][qt2], 0, 0, 0);
      o[dt][qt2] = __builtin_amdgcn_mfma_f32_16x16x32_bf16(vf1, pf1.v, o[dt][qt2], 0, 0, 0);
    }
  }
}

// ---- Flash attention (S^T form, exp2-domain, no-max softmax, register-P) ----
__global__ __launch_bounds__(256, 4) void attn_kernel(
    const bf16* __restrict__ qk, const bf16* __restrict__ vt,
    bf16* __restrict__ aout) {
  int bh = blockIdx.x;   // 0..63 == b*16+h
  int qt = blockIdx.y;   // 0..15
  int bb = bh >> 4, h = bh & 15;
  const bf16* Qg = qk + (size_t)bb * SEQ * 2048 + h * DHEAD;
  const bf16* Kg = Qg + D_MODEL;
  const bf16* Vg = vt + (size_t)bh * DHEAD * SEQ;

  __shared__ __attribute__((aligned(16))) bf16 Qlds[128 * 64];   // 16 KB; KV buf1 after prologue
  __shared__ __attribute__((aligned(16))) bf16 Klds[64 * 64];    //  8 KB; KV buf0 K
  __shared__ __attribute__((aligned(16))) bf16 Vlds[64 * 64];    //  8 KB; KV buf0 V

  int tid = threadIdx.x, wave = tid >> 6, lane = tid & 63;
  int prow = tid >> 3, pch = tid & 7;
  int lch8 = ((pch ^ (prow & 7)) << 3);
  int frow = lane & 15, quad = lane >> 4;
  int e0 = ((quad ^ (frow & 7)) << 3);
  int q0 = qt * 128;

  bf16* K0 = Klds;  bf16* V0 = Vlds;
  bf16* K1 = Qlds;  bf16* V1 = Qlds + 64 * 64;

  const bf16* Kp0 = Kg + (size_t)prow * 2048 + lch8;
  const bf16* Kp1 = Kg + (size_t)(32 + prow) * 2048 + lch8;
  const bf16* Vp0 = Vg + (size_t)prow * SEQ + lch8;
  const bf16* Vp1 = Vg + (size_t)(32 + prow) * SEQ + lch8;
  const size_t KT = (size_t)1 << 17;

#pragma unroll
  for (int s2 = 0; s2 < 4; s2++)
    load_lds16(Qg + (size_t)(q0 + s2 * 32 + prow) * 2048 + lch8,
               (char*)Qlds + s2 * 4096 + tid * 16);
  __syncthreads();
  bf16x8 qf[2][2];
#pragma unroll
  for (int qt2 = 0; qt2 < 2; qt2++)
#pragma unroll
    for (int kk = 0; kk < 2; kk++)
      qf[qt2][kk] =
          *(const bf16x8*)&Qlds[(wave * 32 + qt2 * 16 + frow) * 64 + (e0 ^ (kk * 32))];
  stage_kv(Kp0, Kp1, Vp0, Vp1, K0, V0, tid);
  __syncthreads();

  f32x4 l4[2] = {};
  f32x4 o[4][2] = {};

#pragma unroll 1
  for (int kt = 0; kt < 30; kt += 2) {
    stage_kv(Kp0 + KT, Kp1 + KT, Vp0 + 64, Vp1 + 64, K1, V1, tid);
    kv_tile(K0, V0, frow, e0, qf, l4, o);
    __syncthreads();
    stage_kv(Kp0 + 2 * KT, Kp1 + 2 * KT, Vp0 + 128, Vp1 + 128, K0, V0, tid);
    kv_tile(K1, V1, frow, e0, qf, l4, o);
    __syncthreads();
    Kp0 += 2 * KT; Kp1 += 2 * KT; Vp0 += 128; Vp1 += 128;
  }
  stage_kv(Kp0 + KT, Kp1 + KT, Vp0 + 64, Vp1 + 64, K1, V1, tid);
  kv_tile(K0, V0, frow, e0, qf, l4, o);
  __syncthreads();
  kv_tile(K1, V1, frow, e0, qf, l4, o);

  float linv[2];
#pragma unroll
  for (int qt2 = 0; qt2 < 2; qt2++) {
    float v = (l4[qt2][0] + l4[qt2][1]) + (l4[qt2][2] + l4[qt2][3]);
    v += __shfl_xor(v, 16, 64);
    v += __shfl_xor(v, 32, 64);
    linv[qt2] = 1.f / v;
  }

  __syncthreads();
  bf16* Tw = (wave == 0) ? Qlds
           : (wave == 1) ? Qlds + 32 * 80
           : (wave == 2) ? Klds : Vlds;
#pragma unroll
  for (int qt2 = 0; qt2 < 2; qt2++)
#pragma unroll
    for (int dt = 0; dt < 4; dt++) {
      ushort4 pk;
      pk.x = f2bf(o[dt][qt2][0] * linv[qt2]);
      pk.y = f2bf(o[dt][qt2][1] * linv[qt2]);
      pk.z = f2bf(o[dt][qt2][2] * linv[qt2]);
      pk.w = f2bf(o[dt][qt2][3] * linv[qt2]);
      *(ushort4*)&Tw[(qt2 * 16 + frow) * 80 + dt * 16 + quad * 4] = pk;
    }
  int rq = lane >> 1, d0 = (lane & 1) * 32;
  size_t grow = (size_t)(bb * SEQ + q0 + wave * 32 + rq);
#pragma unroll
  for (int i = 0; i < 4; i++) {
    bf16x8 v8 = *(const bf16x8*)&Tw[rq * 80 + d0 + i * 8];
    *(bf16x8*)&aout[grow * D_MODEL + h * DHEAD + d0 + i * 8] = v8;
  }
}

extern "C" void kernel_launch(void* const* d_in, const int* in_sizes, int n_in,
                              void* d_out, int out_size, void* d_ws, size_t ws_size,
                              hipStream_t stream) {
  const float* x     = (const float*)d_in[0];
  const float* w_qkv = (const float*)d_in[1];
  const float* b_qkv = (const float*)d_in[2];
  const float* w_fc  = (const float*)d_in[3];
  const float* b_fc  = (const float*)d_in[4];
  const float* ln_g  = (const float*)d_in[5];
  const float* ln_b  = (const float*)d_in[6];
  float* out = (float*)d_out;

  char* ws = (char*)d_ws;
  bf16* xn    = (bf16*)(ws);                 // 16 MB (aliased by aout after gemm1)
  bf16* wqkvT = (bf16*)(ws + (16u << 20));   //  6 MB
  bf16* wfcT  = (bf16*)(ws + (22u << 20));   //  2 MB
  bf16* qk    = (bf16*)(ws + (24u << 20));   // 32 MB
  bf16* vt    = (bf16*)(ws + (56u << 20));   // 16 MB -> 72 MB total
  bf16* aout  = (bf16*)(ws);                 // reuses xn region

  prep_kernel<<<2048 + 4096, 256, 0, stream>>>(
      x, ln_g, ln_b, xn, w_qkv, wqkvT, w_fc, wfcT);
  gemm_bt<1, 0, bf16><<<(NROWS / 128) * (3 * D_MODEL / 128), 256, 0, stream>>>(
      xn, wqkvT, b_qkv, nullptr, qk, vt, NROWS, 3 * D_MODEL, D_MODEL);
  attn_kernel<<<dim3(NB * NHEAD, SEQ / 128), 256, 0, stream>>>(qk, vt, aout);
  gemm_fc64<<<1024, 256, 0, stream>>>(aout, wfcT, b_fc, x, out);
}

// Round 10
// 263.838 us; speedup vs baseline: 1.0718x; 1.0047x over previous
//
#include <hip/hip_runtime.h>
#include <hip/hip_bf16.h>
#include <cstdint>
#include <cstddef>

using bf16 = __hip_bfloat16;
typedef __attribute__((ext_vector_type(4))) float f32x4;
typedef __attribute__((ext_vector_type(8))) short bf16x8;

#define D_MODEL 1024
#define SEQ     2048
#define NB      4
#define NHEAD   16
#define DHEAD   64
#define NROWS   (NB * SEQ)   // 8192

__device__ __forceinline__ void load_lds16(const void* g, void* l) {
  __builtin_amdgcn_global_load_lds(
      (const __attribute__((address_space(1))) unsigned int*)g,
      (__attribute__((address_space(3))) unsigned int*)l, 16, 0, 0);
}

__device__ __forceinline__ unsigned short f2bf(float f) {
  bf16 h = __float2bfloat16(f);
  return *(unsigned short*)&h;
}

// Truncating pack: two f32 -> packed bf16 pair (low = a, high = b). ~1 v_perm.
__device__ __forceinline__ unsigned pk_trunc(float a, float b) {
  union { float f; unsigned u; } ca, cb;
  ca.f = a; cb.f = b;
  return (ca.u >> 16) | (cb.u & 0xffff0000u);
}

// ---- Fused prep: LN (blocks 0..2047) + weight transpose (blocks 2048..6143) ----
__global__ __launch_bounds__(256) void prep_kernel(
    const float* __restrict__ x, const float* __restrict__ g,
    const float* __restrict__ bb, bf16* __restrict__ xn,
    const float* __restrict__ w_qkv, bf16* __restrict__ wqkvT,
    const float* __restrict__ w_fc, bf16* __restrict__ wfcT) {
  __shared__ float tile[32][33];
  if (blockIdx.x < 2048) {
    // ---------- LayerNorm: fp32 in, bf16 out; one wave per row ----------
    int row  = blockIdx.x * 4 + (threadIdx.x >> 6);
    int lane = threadIdx.x & 63;
    const float4* xr = (const float4*)(x + (size_t)row * D_MODEL);
    float v[16], s = 0.f;
#pragma unroll
    for (int i = 0; i < 4; i++) {
      float4 t = xr[lane + 64 * i];
      v[4 * i] = t.x; v[4 * i + 1] = t.y; v[4 * i + 2] = t.z; v[4 * i + 3] = t.w;
      s += t.x + t.y + t.z + t.w;
    }
#pragma unroll
    for (int off = 32; off; off >>= 1) s += __shfl_xor(s, off, 64);
    float mean = s * (1.f / D_MODEL);
    float vs = 0.f;
#pragma unroll
    for (int i = 0; i < 16; i++) { float d = v[i] - mean; vs += d * d; }
#pragma unroll
    for (int off = 32; off; off >>= 1) vs += __shfl_xor(vs, off, 64);
    float rstd = rsqrtf(vs * (1.f / D_MODEL) + 1e-5f);
    ushort4* op = (ushort4*)(xn + (size_t)row * D_MODEL);
#pragma unroll
    for (int i = 0; i < 4; i++) {
      float4 gv = ((const float4*)g)[lane + 64 * i];
      float4 bv = ((const float4*)bb)[lane + 64 * i];
      ushort4 o;
      o.x = f2bf((v[4 * i]     - mean) * rstd * gv.x + bv.x);
      o.y = f2bf((v[4 * i + 1] - mean) * rstd * gv.y + bv.y);
      o.z = f2bf((v[4 * i + 2] - mean) * rstd * gv.z + bv.z);
      o.w = f2bf((v[4 * i + 3] - mean) * rstd * gv.w + bv.w);
      op[lane + 64 * i] = o;
    }
  } else {
    // ------ Transpose fp32 in[1024][C] -> bf16 out[C][1024] (32x32 tiles) ------
    int b2 = blockIdx.x - 2048;       // 0..4095
    int bx = b2 & 127, by = b2 >> 7;  // bx: col-block, by: row-block (32 rows)
    const float* in; bf16* out; int C, c0;
    if (bx < 96) { in = w_qkv; out = wqkvT; C = 3072; c0 = bx * 32; }
    else         { in = w_fc;  out = wfcT;  C = 1024; c0 = (bx - 96) * 32; }
    int r0 = by * 32;
    int tx = threadIdx.x & 31, ty = threadIdx.x >> 5;
    for (int i = ty; i < 32; i += 8)
      tile[i][tx] = in[(size_t)(r0 + i) * C + c0 + tx];
    __syncthreads();
    for (int i = ty; i < 32; i += 8)
      out[(size_t)(c0 + i) * 1024 + r0 + tx] = __float2bfloat16(tile[tx][i]);
  }
}

__device__ __forceinline__ void store_ct(bf16* p, float v)  { *p = __float2bfloat16(v); }
__device__ __forceinline__ void store_ct(float* p, float v) { *p = v; }

// ------- GEMM: C[M,N] = A[M,K](bf16) @ Bt[N,K](bf16)^T + bias (r3-exact) -------
// BK=64, XOR-swizzled LDS, 2-barrier loop, 128x128 tile. Used for the QKV gemm.
template <int SPLIT, int RESID, typename CT>
__global__ __launch_bounds__(256) void gemm_bt(
    const bf16* __restrict__ A, const bf16* __restrict__ Bt,
    const float* __restrict__ bias, const float* __restrict__ resid,
    CT* __restrict__ C, bf16* __restrict__ vt, int M, int N, int K) {
  __shared__ __attribute__((aligned(16))) bf16 Alds[128 * 64];  // 16 KB
  __shared__ __attribute__((aligned(16))) bf16 Blds[128 * 64];  // 16 KB
  int tid = threadIdx.x, wave = tid >> 6, lane = tid & 63;
  int ntiles = N >> 7;
  int bm = blockIdx.x / ntiles, bn = blockIdx.x % ntiles;
  int m0 = bm << 7, n0 = bn << 7;
  int wm = (wave >> 1) << 6, wn = (wave & 1) << 6;
  int srow = tid >> 3;                        // 0..31 (row within 32-row stage block)
  int sw8  = (((tid & 7) ^ (srow & 7)) << 3); // swizzled source chunk (elements)
  int frow = lane & 15, quad = lane >> 4;
  const bf16* Ap[4];
  const bf16* Bp[4];
#pragma unroll
  for (int s = 0; s < 4; s++) {
    Ap[s] = A  + (size_t)(m0 + s * 32 + srow) * K + sw8;
    Bp[s] = Bt + (size_t)(n0 + s * 32 + srow) * K + sw8;
  }
  f32x4 acc[4][4] = {};
  for (int k0 = 0; k0 < K; k0 += 64) {
    __syncthreads();
#pragma unroll
    for (int s = 0; s < 4; s++) {
      load_lds16(Ap[s], (char*)Alds + s * 4096 + tid * 16);
      load_lds16(Bp[s], (char*)Blds + s * 4096 + tid * 16);
      Ap[s] += 64; Bp[s] += 64;
    }
    __syncthreads();
    bf16x8 af[4][2], bv[4][2];
#pragma unroll
    for (int i = 0; i < 4; i++)
#pragma unroll
      for (int kk = 0; kk < 2; kk++) {
        int e = (((kk * 4 + quad) ^ (frow & 7)) << 3);
        af[i][kk] = *(const bf16x8*)&Alds[(wm + i * 16 + frow) * 64 + e];
        bv[i][kk] = *(const bf16x8*)&Blds[(wn + i * 16 + frow) * 64 + e];
      }
#pragma unroll
    for (int i = 0; i < 4; i++)
#pragma unroll
      for (int j = 0; j < 4; j++) {
        acc[i][j] = __builtin_amdgcn_mfma_f32_16x16x32_bf16(af[i][0], bv[j][0], acc[i][j], 0, 0, 0);
        acc[i][j] = __builtin_amdgcn_mfma_f32_16x16x32_bf16(af[i][1], bv[j][1], acc[i][j], 0, 0, 0);
      }
  }
#pragma unroll
  for (int i = 0; i < 4; i++) {
    int row0 = m0 + wm + i * 16 + (quad << 2);
#pragma unroll
    for (int j = 0; j < 4; j++) {
      int col = n0 + wn + j * 16 + frow;
      float bvs = bias[col];
      if (SPLIT && col >= 2048) {           // V third -> permuted transposed vt
        int hd = col - 2048;
        int b = row0 >> 11, seq0 = row0 & 2047;
        int within = seq0 & 63, mt = within >> 4, q4 = (within >> 2) & 3;
        int pos = (seq0 & ~63) + ((mt >> 1) << 5) + (q4 << 3) + ((mt & 1) << 2);
        ushort4 pk;
        pk.x = f2bf(acc[i][j][0] + bvs);
        pk.y = f2bf(acc[i][j][1] + bvs);
        pk.z = f2bf(acc[i][j][2] + bvs);
        pk.w = f2bf(acc[i][j][3] + bvs);
        *(ushort4*)&vt[((size_t)(b * 1024 + hd)) * SEQ + pos] = pk;
      } else {
        int stride = SPLIT ? 2048 : N;
        // Q pre-scale: 1/sqrt(64) * log2(e) -> scores come out in exp2 domain
        float scale = (SPLIT && col < 1024) ? 0.18033688f : 1.0f;
#pragma unroll
        for (int r = 0; r < 4; r++) {
          size_t idx = (size_t)(row0 + r) * stride + col;
          float val = (acc[i][j][r] + bvs) * scale;
          if (RESID) val += resid[idx];
          store_ct(&C[idx], val);
        }
      }
    }
  }
}

// ------- FC GEMM, 128x64 tile, BK=128: out = aout @ wfcT^T + b_fc + x -------
// FC is pinned at ~75 us across 128^2 / 128x64 / wave-autonomous variants ->
// per-K-iteration exposed latency dominates (work/iter is tiny), not occupancy
// or schedule. BK=128 halves the iteration count (16 -> 8) at the same total
// load bytes. LDS 32K(A)+16K(B) = 48 KB -> 3 blocks/CU (m132's BK=128 penalty
// was the 64 KB/2-block case; doesn't apply here). Swizzle: rows of 128 elems
// = two 64-elem k-halves, each staged/read with the byte-identical XOR scheme
// (chunk bit3 = k-half, low 3 bits ^ row&7). Accumulation order over k equals
// two successive BK=64 iterations -> bit-identical numerics.
__global__ __launch_bounds__(256) void gemm_fc128(
    const bf16* __restrict__ A, const bf16* __restrict__ Bt,
    const float* __restrict__ bias, const float* __restrict__ resid,
    float* __restrict__ out) {
  __shared__ __attribute__((aligned(16))) bf16 Alds[128 * 128]; // 32 KB
  __shared__ __attribute__((aligned(16))) bf16 Blds[64 * 128];  // 16 KB
  int tid = threadIdx.x, wave = tid >> 6, lane = tid & 63;
  int bm = blockIdx.x >> 4, bn = blockIdx.x & 15;   // 64 x 16 = 1024 blocks
  int m0 = bm << 7, n0 = bn << 6;
  int wm = (wave >> 1) << 6, wn = (wave & 1) << 5;  // wave tile 64x32
  int frow = lane & 15, quad = lane >> 4;
  // Staging: 4 KB group = 16 rows x 256 B. Thread t -> row t>>4, chunk t&15.
  int srow = tid >> 4;                 // 0..15
  int c = tid & 15;
  int sw = (((c & 8) | ((c & 7) ^ (srow & 7))) << 3);  // source col (elems)
  const bf16* Ap[8];
  const bf16* Bp[4];
#pragma unroll
  for (int s = 0; s < 8; s++)
    Ap[s] = A + (size_t)(m0 + s * 16 + srow) * 1024 + sw;
#pragma unroll
  for (int s = 0; s < 4; s++)
    Bp[s] = Bt + (size_t)(n0 + s * 16 + srow) * 1024 + sw;
  f32x4 acc[4][2] = {};
  for (int k0 = 0; k0 < 1024; k0 += 128) {
    __syncthreads();
#pragma unroll
    for (int s = 0; s < 8; s++) {
      load_lds16(Ap[s], (char*)Alds + s * 4096 + tid * 16);
      Ap[s] += 128;
    }
#pragma unroll
    for (int s = 0; s < 4; s++) {
      load_lds16(Bp[s], (char*)Blds + s * 4096 + tid * 16);
      Bp[s] += 128;
    }
    __syncthreads();
#pragma unroll
    for (int kk = 0; kk < 4; kk++) {
      // global chunk = kk*4+quad; LDS chunk = (c&8) | ((c&7) ^ (row&7))
      int e = (((kk >= 2 ? 8 : 0) | ((((kk & 1) * 4) + quad) ^ (frow & 7))) << 3);
      bf16x8 af[4], bv[2];
#pragma unroll
      for (int i = 0; i < 4; i++)
        af[i] = *(const bf16x8*)&Alds[(wm + i * 16 + frow) * 128 + e];
#pragma unroll
      for (int j = 0; j < 2; j++)
        bv[j] = *(const bf16x8*)&Blds[(wn + j * 16 + frow) * 128 + e];
#pragma unroll
      for (int i = 0; i < 4; i++)
#pragma unroll
        for (int j = 0; j < 2; j++)
          acc[i][j] = __builtin_amdgcn_mfma_f32_16x16x32_bf16(af[i], bv[j], acc[i][j], 0, 0, 0);
    }
  }
#pragma unroll
  for (int i = 0; i < 4; i++) {
    int row0 = m0 + wm + i * 16 + (quad << 2);
#pragma unroll
    for (int j = 0; j < 2; j++) {
      int col = n0 + wn + j * 16 + frow;
      float bvs = bias[col];
#pragma unroll
      for (int r = 0; r < 4; r++) {
        size_t idx = (size_t)(row0 + r) * 1024 + col;
        out[idx] = (acc[i][j][r] + bvs) + resid[idx];
      }
    }
  }
}

// ---- Flash attention helpers (round-3 best: simple dbuf, one barrier/tile) ----

__device__ __forceinline__ void stage_kv(
    const bf16* Kp0, const bf16* Kp1, const bf16* Vp0, const bf16* Vp1,
    bf16* KB, bf16* VB, int tid) {
  load_lds16(Kp0, (char*)KB + tid * 16);
  load_lds16(Kp1, (char*)KB + 4096 + tid * 16);
  load_lds16(Vp0, (char*)VB + tid * 16);
  load_lds16(Vp1, (char*)VB + 4096 + tid * 16);
}

// One KV tile: S^T = K @ Q^T; p = 2^s packed to bf16 in-register; O^T += V^T @ P^T.
__device__ __forceinline__ void kv_tile(
    const bf16* KL, const bf16* VL, int frow, int e0,
    const bf16x8 (&qf)[2][2], f32x4 (&l4)[2], f32x4 (&o)[4][2]) {
  f32x4 s[4][2] = {};
#pragma unroll
  for (int mt = 0; mt < 4; mt++) {
    bf16x8 af0 = *(const bf16x8*)&KL[(mt * 16 + frow) * 64 + e0];
    bf16x8 af1 = *(const bf16x8*)&KL[(mt * 16 + frow) * 64 + (e0 ^ 32)];
#pragma unroll
    for (int qt2 = 0; qt2 < 2; qt2++) {
      s[mt][qt2] = __builtin_amdgcn_mfma_f32_16x16x32_bf16(af0, qf[qt2][0], s[mt][qt2], 0, 0, 0);
      s[mt][qt2] = __builtin_amdgcn_mfma_f32_16x16x32_bf16(af1, qf[qt2][1], s[mt][qt2], 0, 0, 0);
    }
  }
  uint2 pk[2][4];
#pragma unroll
  for (int qt2 = 0; qt2 < 2; qt2++)
#pragma unroll
    for (int mt = 0; mt < 4; mt++) {
      f32x4 pv;
      pv[0] = __builtin_amdgcn_exp2f(s[mt][qt2][0]);
      pv[1] = __builtin_amdgcn_exp2f(s[mt][qt2][1]);
      pv[2] = __builtin_amdgcn_exp2f(s[mt][qt2][2]);
      pv[3] = __builtin_amdgcn_exp2f(s[mt][qt2][3]);
      l4[qt2] += pv;
      pk[qt2][mt].x = pk_trunc(pv[0], pv[1]);
      pk[qt2][mt].y = pk_trunc(pv[2], pv[3]);
    }
#pragma unroll
  for (int dt = 0; dt < 4; dt++) {
    bf16x8 vf0 = *(const bf16x8*)&VL[(dt * 16 + frow) * 64 + e0];
    bf16x8 vf1 = *(const bf16x8*)&VL[(dt * 16 + frow) * 64 + (e0 ^ 32)];
#pragma unroll
    for (int qt2 = 0; qt2 < 2; qt2++) {
      union { unsigned u[4]; bf16x8 v; } pf0, pf1;
      pf0.u[0] = pk[qt2][0].x; pf0.u[1] = pk[qt2][0].y;
      pf0.u[2] = pk[qt2][1].x; pf0.u[3] = pk[qt2][1].y;
      pf1.u[0] = pk[qt2][2].x; pf1.u[1] = pk[qt2][2].y;
      pf1.u[2] = pk[qt2][3].x; pf1.u[3] = pk[qt2][3].y;
      o[dt][qt2] = __builtin_amdgcn_mfma_f32_16x16x32_bf16(vf0, pf0.v, o[dt][qt2], 0, 0, 0);
      o[dt][qt2] = __builtin_amdgcn_mfma_f32_16x16x32_bf16(vf1, pf1.v, o[dt][qt2], 0, 0, 0);
    }
  }
}

// ---- Flash attention (S^T form, exp2-domain, no-max softmax, register-P) ----
__global__ __launch_bounds__(256, 4) void attn_kernel(
    const bf16* __restrict__ qk, const bf16* __restrict__ vt,
    bf16* __restrict__ aout) {
  int bh = blockIdx.x;   // 0..63 == b*16+h
  int qt = blockIdx.y;   // 0..15
  int bb = bh >> 4, h = bh & 15;
  const bf16* Qg = qk + (size_t)bb * SEQ * 2048 + h * DHEAD;
  const bf16* Kg = Qg + D_MODEL;
  const bf16* Vg = vt + (size_t)bh * DHEAD * SEQ;

  __shared__ __attribute__((aligned(16))) bf16 Qlds[128 * 64];   // 16 KB; KV buf1 after prologue
  __shared__ __attribute__((aligned(16))) bf16 Klds[64 * 64];    //  8 KB; KV buf0 K
  __shared__ __attribute__((aligned(16))) bf16 Vlds[64 * 64];    //  8 KB; KV buf0 V

  int tid = threadIdx.x, wave = tid >> 6, lane = tid & 63;
  int prow = tid >> 3, pch = tid & 7;
  int lch8 = ((pch ^ (prow & 7)) << 3);
  int frow = lane & 15, quad = lane >> 4;
  int e0 = ((quad ^ (frow & 7)) << 3);
  int q0 = qt * 128;

  bf16* K0 = Klds;  bf16* V0 = Vlds;
  bf16* K1 = Qlds;  bf16* V1 = Qlds + 64 * 64;

  const bf16* Kp0 = Kg + (size_t)prow * 2048 + lch8;
  const bf16* Kp1 = Kg + (size_t)(32 + prow) * 2048 + lch8;
  const bf16* Vp0 = Vg + (size_t)prow * SEQ + lch8;
  const bf16* Vp1 = Vg + (size_t)(32 + prow) * SEQ + lch8;
  const size_t KT = (size_t)1 << 17;

#pragma unroll
  for (int s2 = 0; s2 < 4; s2++)
    load_lds16(Qg + (size_t)(q0 + s2 * 32 + prow) * 2048 + lch8,
               (char*)Qlds + s2 * 4096 + tid * 16);
  __syncthreads();
  bf16x8 qf[2][2];
#pragma unroll
  for (int qt2 = 0; qt2 < 2; qt2++)
#pragma unroll
    for (int kk = 0; kk < 2; kk++)
      qf[qt2][kk] =
          *(const bf16x8*)&Qlds[(wave * 32 + qt2 * 16 + frow) * 64 + (e0 ^ (kk * 32))];
  stage_kv(Kp0, Kp1, Vp0, Vp1, K0, V0, tid);
  __syncthreads();

  f32x4 l4[2] = {};
  f32x4 o[4][2] = {};

#pragma unroll 1
  for (int kt = 0; kt < 30; kt += 2) {
    stage_kv(Kp0 + KT, Kp1 + KT, Vp0 + 64, Vp1 + 64, K1, V1, tid);
    kv_tile(K0, V0, frow, e0, qf, l4, o);
    __syncthreads();
    stage_kv(Kp0 + 2 * KT, Kp1 + 2 * KT, Vp0 + 128, Vp1 + 128, K0, V0, tid);
    kv_tile(K1, V1, frow, e0, qf, l4, o);
    __syncthreads();
    Kp0 += 2 * KT; Kp1 += 2 * KT; Vp0 += 128; Vp1 += 128;
  }
  stage_kv(Kp0 + KT, Kp1 + KT, Vp0 + 64, Vp1 + 64, K1, V1, tid);
  kv_tile(K0, V0, frow, e0, qf, l4, o);
  __syncthreads();
  kv_tile(K1, V1, frow, e0, qf, l4, o);

  float linv[2];
#pragma unroll
  for (int qt2 = 0; qt2 < 2; qt2++) {
    float v = (l4[qt2][0] + l4[qt2][1]) + (l4[qt2][2] + l4[qt2][3]);
    v += __shfl_xor(v, 16, 64);
    v += __shfl_xor(v, 32, 64);
    linv[qt2] = 1.f / v;
  }

  __syncthreads();
  bf16* Tw = (wave == 0) ? Qlds
           : (wave == 1) ? Qlds + 32 * 80
           : (wave == 2) ? Klds : Vlds;
#pragma unroll
  for (int qt2 = 0; qt2 < 2; qt2++)
#pragma unroll
    for (int dt = 0; dt < 4; dt++) {
      ushort4 pk;
      pk.x = f2bf(o[dt][qt2][0] * linv[qt2]);
      pk.y = f2bf(o[dt][qt2][1] * linv[qt2]);
      pk.z = f2bf(o[dt][qt2][2] * linv[qt2]);
      pk.w = f2bf(o[dt][qt2][3] * linv[qt2]);
      *(ushort4*)&Tw[(qt2 * 16 + frow) * 80 + dt * 16 + quad * 4] = pk;
    }
  int rq = lane >> 1, d0 = (lane & 1) * 32;
  size_t grow = (size_t)(bb * SEQ + q0 + wave * 32 + rq);
#pragma unroll
  for (int i = 0; i < 4; i++) {
    bf16x8 v8 = *(const bf16x8*)&Tw[rq * 80 + d0 + i * 8];
    *(bf16x8*)&aout[grow * D_MODEL + h * DHEAD + d0 + i * 8] = v8;
  }
}

extern "C" void kernel_launch(void* const* d_in, const int* in_sizes, int n_in,
                              void* d_out, int out_size, void* d_ws, size_t ws_size,
                              hipStream_t stream) {
  const float* x     = (const float*)d_in[0];
  const float* w_qkv = (const float*)d_in[1];
  const float* b_qkv = (const float*)d_in[2];
  const float* w_fc  = (const float*)d_in[3];
  const float* b_fc  = (const float*)d_in[4];
  const float* ln_g  = (const float*)d_in[5];
  const float* ln_b  = (const float*)d_in[6];
  float* out = (float*)d_out;

  char* ws = (char*)d_ws;
  bf16* xn    = (bf16*)(ws);                 // 16 MB (aliased by aout after gemm1)
  bf16* wqkvT = (bf16*)(ws + (16u << 20));   //  6 MB
  bf16* wfcT  = (bf16*)(ws + (22u << 20));   //  2 MB
  bf16* qk    = (bf16*)(ws + (24u << 20));   // 32 MB
  bf16* vt    = (bf16*)(ws + (56u << 20));   // 16 MB -> 72 MB total
  bf16* aout  = (bf16*)(ws);                 // reuses xn region

  prep_kernel<<<2048 + 4096, 256, 0, stream>>>(
      x, ln_g, ln_b, xn, w_qkv, wqkvT, w_fc, wfcT);
  gemm_bt<1, 0, bf16><<<(NROWS / 128) * (3 * D_MODEL / 128), 256, 0, stream>>>(
      xn, wqkvT, b_qkv, nullptr, qk, vt, NROWS, 3 * D_MODEL, D_MODEL);
  attn_kernel<<<dim3(NB * NHEAD, SEQ / 128), 256, 0, stream>>>(qk, vt, aout);
  gemm_fc128<<<1024, 256, 0, stream>>>(aout, wfcT, b_fc, x, out);
}